// Round 12
// baseline (165.974 us; speedup 1.0000x reference)
//
#include <hip/hip_runtime.h>

#define L_LEN   262144
#define OUT_LEN 262142
#define NTOT    (32.0 * 262142.0)

typedef float v4f __attribute__((ext_vector_type(4)));

struct KPtrs { const float* p[12]; };

// ============ K1: block 0 = self-pool + MLP -> Kraw ; blocks 1..1024 = autocorr stats ============
// (unchanged from R11 — validated). part SoA: part[v*1024 + (blk-1)], v=0 -> X, v=1+l -> R_l.
__global__ __launch_bounds__(256, 4) void stats_mlp_kernel(const float* __restrict__ x,
                                                           const float* __restrict__ w1,
                                                           const float* __restrict__ b1,
                                                           const float* __restrict__ w2,
                                                           const float* __restrict__ b2,
                                                           KPtrs kp,
                                                           float* __restrict__ part,
                                                           float* __restrict__ Kraw) {
    int tid = threadIdx.x;

    if (blockIdx.x == 0) {
        __shared__ float pooledL[256];
        __shared__ float h[128];
        __shared__ float lgt[12];
        __shared__ float sm[12];
        {
            float s = 0.0f;
            const float4* xq = (const float4*)(x + (size_t)1024 * tid);
            #pragma unroll 8
            for (int i = 0; i < 256; ++i) {
                float4 v = xq[i];
                s += (v.x + v.y) + (v.z + v.w);
            }
            pooledL[tid] = s * (1.0f / 1024.0f);
        }
        __syncthreads();
        int w = tid >> 6, lane = tid & 63;
        float4 pv = *(const float4*)&pooledL[4 * lane];
        for (int i = 0; i < 32; ++i) {
            int t = w * 32 + i;
            float4 wv = ((const float4*)(w1 + t * 256))[lane];
            float p = wv.x*pv.x + wv.y*pv.y + wv.z*pv.z + wv.w*pv.w;
            #pragma unroll
            for (int off = 32; off; off >>= 1) p += __shfl_down(p, off);
            if (lane == 0) h[t] = fmaxf(p + b1[t], 0.0f);
        }
        __syncthreads();
        for (int f = w; f < 12; f += 4) {
            float2 wv = ((const float2*)(w2 + f * 128))[lane];
            float p = wv.x * h[2*lane] + wv.y * h[2*lane + 1];
            #pragma unroll
            for (int off = 32; off; off >>= 1) p += __shfl_down(p, off);
            if (lane == 0) lgt[f] = p + b2[f];
        }
        __syncthreads();
        if (tid == 0) {
            float m = lgt[0];
            #pragma unroll
            for (int i = 1; i < 12; ++i) m = fmaxf(m, lgt[i]);
            float e[12]; float sum = 0.0f;
            #pragma unroll
            for (int i = 0; i < 12; ++i) { e[i] = expf(lgt[i] - m); sum += e[i]; }
            float inv = 1.0f / sum;
            #pragma unroll
            for (int i = 0; i < 12; ++i) sm[i] = e[i] * inv;
        }
        __syncthreads();
        constexpr int KSa[12] = {3,3,3,5,5,7,7,7,9,9,11,11};
        if (tid < 220) {
            int q = tid / 44, r = tid % 44, c = r / 11, j = r % 11;
            int kmax = 2 * q + 3;
            float v = 0.0f;
            #pragma unroll
            for (int i = 0; i < 12; ++i) {
                int k = KSa[i];
                if (k <= kmax && j < k) v = fmaf(sm[i], kp.p[i][c * k + j], v);
            }
            Kraw[tid] = v;
        }
        return;
    }

    __shared__ float xt[2064];
    float X = 0.0f, R[11];
    #pragma unroll
    for (int l = 0; l < 11; ++l) R[l] = 0.0f;

    for (int it = 0; it < 4; ++it) {
        int T = (blockIdx.x - 1) * 4 + it;
        int row = T >> 7, seg = T & 127;
        int base = seg << 11;
        const float* xb = x + row * L_LEN;
        *(float4*)&xt[4*tid]        = *(const float4*)(xb + base + 4*tid);
        *(float4*)&xt[1024 + 4*tid] = *(const float4*)(xb + base + 1024 + 4*tid);
        if (tid < 3) {
            float4 v = {0.f,0.f,0.f,0.f};
            if (seg < 127) v = *(const float4*)(xb + base + 2048 + 4*tid);
            *(float4*)&xt[2048 + 4*tid] = v;
        }
        __syncthreads();

        float xv[18];
        const float4* xr = (const float4*)&xt[8*tid];
        #pragma unroll
        for (int i = 0; i < 4; ++i) {
            float4 a = xr[i];
            xv[4*i]=a.x; xv[4*i+1]=a.y; xv[4*i+2]=a.z; xv[4*i+3]=a.w;
        }
        float2 a4 = *(const float2*)&xt[8*tid + 16];
        xv[16]=a4.x; xv[17]=a4.y;

        float s8 = 0.0f;
        #pragma unroll
        for (int p = 0; p < 8; ++p) s8 += xv[p];
        X += s8;
        #pragma unroll
        for (int l = 0; l < 11; ++l) {
            float r = 0.0f;
            #pragma unroll
            for (int p = 0; p < 8; ++p) r = fmaf(xv[p], xv[p+l], r);
            R[l] += r;
        }
        __syncthreads();
    }

    #pragma unroll
    for (int off = 32; off; off >>= 1) {
        X += __shfl_down(X, off);
        #pragma unroll
        for (int l = 0; l < 11; ++l) R[l] += __shfl_down(R[l], off);
    }
    __shared__ float red[4][12];
    int wave = tid >> 6;
    if ((tid & 63) == 0) {
        red[wave][0] = X;
        #pragma unroll
        for (int l = 0; l < 11; ++l) red[wave][1+l] = R[l];
    }
    __syncthreads();
    if (tid < 12)
        part[tid * 1024 + (blockIdx.x - 1)] = red[0][tid] + red[1][tid] + red[2][tid] + red[3][tid];
}

// ============ K2: fold prologue + BARRIER-FREE channel-split streaming write ============
// grid 2048 x 256, launch_bounds(256,8) -> 8 blocks/CU. c = blk>>9 (block-uniform),
// rowg = (blk>>8)&1 -> rows [16g..16g+15], i = (blk&255)*256 + tid (quad index).
// Thread: per row, 4 consecutive outputs of channel c: 4 aligned float4 loads (L1/L3),
// 44 FMA (taps in SGPR via readfirstlane), one 16B-aligned lane-contiguous dwordx4 store.
// Odd channels shifted +2 -> all stores aligned. No barriers after the fold prologue.
__global__ __launch_bounds__(256, 8) void write_fold_kernel(const float* __restrict__ x,
                                                            const float* __restrict__ Kraw,
                                                            const float* __restrict__ part,
                                                            const float* __restrict__ gamma,
                                                            const float* __restrict__ beta,
                                                            float* __restrict__ out) {
    __shared__ float KrLds[220];
    __shared__ double vals[12];
    __shared__ float foldK[4][11];
    __shared__ float gLds[4];
    __shared__ float biasLds[4];
    int tid = threadIdx.x;
    int blk = blockIdx.x;
    int c    = blk >> 9;           // channel, uniform per block
    int rowg = (blk >> 8) & 1;     // row group
    int i    = (blk & 255) * 256 + tid;   // quad index 0..65535
    int w = tid >> 6, lane = tid & 63;

    // ---- fold prologue (2 barriers, no stores in flight yet) ----
    if (tid < 220) KrLds[tid] = Kraw[tid];
    for (int v = w; v < 12; v += 4) {
        double d = 0.0;
        #pragma unroll 4
        for (int k = 0; k < 16; ++k) d += (double)part[v*1024 + k*64 + lane];
        #pragma unroll
        for (int off = 32; off; off >>= 1) d += __shfl_down(d, off);
        if (lane == 0) vals[v] = d;
    }
    __syncthreads();
    if (tid < 4) {
        int cc = tid;
        const float* K44 = KrLds + 176;
        double sK = 0.0;
        for (int j = 0; j < 11; ++j) sK += (double)K44[cc*11 + j];
        double mean = sK * vals[0] / NTOT;
        double ex2 = 0.0;
        for (int l = 0; l < 11; ++l) {
            double A = 0.0;
            for (int j = 0; j + l < 11; ++j) A += (double)K44[cc*11+j] * (double)K44[cc*11+j+l];
            ex2 += (l ? 2.0 : 1.0) * A * vals[1+l];
        }
        ex2 /= NTOT;
        double var = ex2 - mean * mean;
        float gg = gamma[cc] * (float)(1.0 / sqrt(var + 1e-5));
        gLds[cc] = gg;
        biasLds[cc] = beta[cc] - (float)mean * gg;
        for (int j = 0; j < 11; ++j) foldK[cc][j] = K44[cc*11 + j] * gg;
    }
    __syncthreads();

    // taps to SGPRs (block-uniform)
    float Ks[11];
    #pragma unroll
    for (int j = 0; j < 11; ++j)
        Ks[j] = __int_as_float(__builtin_amdgcn_readfirstlane(__float_as_int(foldK[c][j])));
    float bias = __int_as_float(__builtin_amdgcn_readfirstlane(__float_as_int(biasLds[c])));
    float gc = gLds[c];
    int sh = (c & 1) ? 2 : 0;

    // ---- streaming loop: 16 rows, no barriers ----
    for (int it = 0; it < 16; ++it) {
        int row = rowg * 16 + it;
        const float* xb = x + (size_t)row * L_LEN;
        float* ob = out + (size_t)(4*row + c) * OUT_LEN;

        if (i <= 65532) {
            float xv[16];
            const float4* xp = (const float4*)(xb + 4*i);
            #pragma unroll
            for (int q = 0; q < 4; ++q) {
                float4 a = xp[q];
                xv[4*q]=a.x; xv[4*q+1]=a.y; xv[4*q+2]=a.z; xv[4*q+3]=a.w;
            }
            float v[4];
            #pragma unroll
            for (int p = 0; p < 4; ++p) {
                float a = bias;
                #pragma unroll
                for (int j = 0; j < 11; ++j) a = fmaf(Ks[j], xv[sh + p + j], a);
                v[p] = fmaxf(a, 0.0f);
            }
            // addr = rowbase + sh + 4i; rowbase%4 = 2c%4, sh cancels -> 16B aligned
            *(v4f*)(ob + sh + 4*i) = (v4f){v[0], v[1], v[2], v[3]};
            if (i == 0 && sh) {
                // head t=0,1 for odd channels (full kernel, rem >> 11)
                for (int t = 0; t < 2; ++t) {
                    float a = bias;
                    #pragma unroll
                    for (int j = 0; j < 11; ++j) a = fmaf(Ks[j], xb[t + j], a);
                    ob[t] = fmaxf(a, 0.0f);
                }
            }
        } else {
            // i in {65533,65534,65535}: per-position cumulative-class scalar path
            #pragma unroll
            for (int p = 0; p < 4; ++p) {
                int t = sh + 4*i + p;
                if (t >= OUT_LEN) continue;
                int rem = L_LEN - t;                  // 3..11
                int q = (rem - 3) >> 1; if (q > 4) q = 4;
                int kmax = 2 * q + 3;
                float a = bias;
                for (int j = 0; j < kmax; ++j)
                    a = fmaf(KrLds[q*44 + c*11 + j] * gc, xb[t + j], a);
                ob[t] = fmaxf(a, 0.0f);
            }
        }
    }
}

extern "C" void kernel_launch(void* const* d_in, const int* in_sizes, int n_in,
                              void* d_out, int out_size, void* d_ws, size_t ws_size,
                              hipStream_t stream) {
    const float* x     = (const float*)d_in[0];
    const float* w1    = (const float*)d_in[1];
    const float* b1    = (const float*)d_in[2];
    const float* w2    = (const float*)d_in[3];
    const float* b2    = (const float*)d_in[4];
    const float* gamma = (const float*)d_in[5];
    const float* beta  = (const float*)d_in[6];
    KPtrs kp;
    for (int i = 0; i < 12; ++i) kp.p[i] = (const float*)d_in[7 + i];
    float* out = (float*)d_out;

    char* ws = (char*)d_ws;
    float* Kraw = (float*)(ws + 1024);      // 220 floats
    float* part = (float*)(ws + 4096);      // 12*1024 floats = 48 KB

    stats_mlp_kernel<<<dim3(1025), dim3(256), 0, stream>>>(x, w1, b1, w2, b2, kp, part, Kraw);
    write_fold_kernel<<<dim3(2048), dim3(256), 0, stream>>>(x, Kraw, part, gamma, beta, out);
}

// Round 13
// 106.232 us; speedup vs baseline: 1.5624x; 1.5624x over previous
//
#include <hip/hip_runtime.h>

#define L_LEN   262144
#define OUT_LEN 262142
#define NTOT    (32.0 * 262142.0)

typedef float v4f __attribute__((ext_vector_type(4)));

struct KPtrs { const float* p[12]; };

// ============ K1: block 0 = self-pool + MLP -> Kraw ; blocks 1..1024 = autocorr stats ============
// (validated R11/R12). part SoA: part[v*1024 + (blk-1)], v=0 -> X, v=1+l -> R_l.
__global__ __launch_bounds__(256, 4) void stats_mlp_kernel(const float* __restrict__ x,
                                                           const float* __restrict__ w1,
                                                           const float* __restrict__ b1,
                                                           const float* __restrict__ w2,
                                                           const float* __restrict__ b2,
                                                           KPtrs kp,
                                                           float* __restrict__ part,
                                                           float* __restrict__ Kraw) {
    int tid = threadIdx.x;

    if (blockIdx.x == 0) {
        __shared__ float pooledL[256];
        __shared__ float h[128];
        __shared__ float lgt[12];
        __shared__ float sm[12];
        {
            float s = 0.0f;
            const float4* xq = (const float4*)(x + (size_t)1024 * tid);
            #pragma unroll 8
            for (int i = 0; i < 256; ++i) {
                float4 v = xq[i];
                s += (v.x + v.y) + (v.z + v.w);
            }
            pooledL[tid] = s * (1.0f / 1024.0f);
        }
        __syncthreads();
        int w = tid >> 6, lane = tid & 63;
        float4 pv = *(const float4*)&pooledL[4 * lane];
        for (int i = 0; i < 32; ++i) {
            int t = w * 32 + i;
            float4 wv = ((const float4*)(w1 + t * 256))[lane];
            float p = wv.x*pv.x + wv.y*pv.y + wv.z*pv.z + wv.w*pv.w;
            #pragma unroll
            for (int off = 32; off; off >>= 1) p += __shfl_down(p, off);
            if (lane == 0) h[t] = fmaxf(p + b1[t], 0.0f);
        }
        __syncthreads();
        for (int f = w; f < 12; f += 4) {
            float2 wv = ((const float2*)(w2 + f * 128))[lane];
            float p = wv.x * h[2*lane] + wv.y * h[2*lane + 1];
            #pragma unroll
            for (int off = 32; off; off >>= 1) p += __shfl_down(p, off);
            if (lane == 0) lgt[f] = p + b2[f];
        }
        __syncthreads();
        if (tid == 0) {
            float m = lgt[0];
            #pragma unroll
            for (int i = 1; i < 12; ++i) m = fmaxf(m, lgt[i]);
            float e[12]; float sum = 0.0f;
            #pragma unroll
            for (int i = 0; i < 12; ++i) { e[i] = expf(lgt[i] - m); sum += e[i]; }
            float inv = 1.0f / sum;
            #pragma unroll
            for (int i = 0; i < 12; ++i) sm[i] = e[i] * inv;
        }
        __syncthreads();
        constexpr int KSa[12] = {3,3,3,5,5,7,7,7,9,9,11,11};
        if (tid < 220) {
            int q = tid / 44, r = tid % 44, c = r / 11, j = r % 11;
            int kmax = 2 * q + 3;
            float v = 0.0f;
            #pragma unroll
            for (int i = 0; i < 12; ++i) {
                int k = KSa[i];
                if (k <= kmax && j < k) v = fmaf(sm[i], kp.p[i][c * k + j], v);
            }
            Kraw[tid] = v;
        }
        return;
    }

    __shared__ float xt[2064];
    float X = 0.0f, R[11];
    #pragma unroll
    for (int l = 0; l < 11; ++l) R[l] = 0.0f;

    for (int it = 0; it < 4; ++it) {
        int T = (blockIdx.x - 1) * 4 + it;
        int row = T >> 7, seg = T & 127;
        int base = seg << 11;
        const float* xb = x + row * L_LEN;
        *(float4*)&xt[4*tid]        = *(const float4*)(xb + base + 4*tid);
        *(float4*)&xt[1024 + 4*tid] = *(const float4*)(xb + base + 1024 + 4*tid);
        if (tid < 3) {
            float4 v = {0.f,0.f,0.f,0.f};
            if (seg < 127) v = *(const float4*)(xb + base + 2048 + 4*tid);
            *(float4*)&xt[2048 + 4*tid] = v;
        }
        __syncthreads();

        float xv[18];
        const float4* xr = (const float4*)&xt[8*tid];
        #pragma unroll
        for (int i = 0; i < 4; ++i) {
            float4 a = xr[i];
            xv[4*i]=a.x; xv[4*i+1]=a.y; xv[4*i+2]=a.z; xv[4*i+3]=a.w;
        }
        float2 a4 = *(const float2*)&xt[8*tid + 16];
        xv[16]=a4.x; xv[17]=a4.y;

        float s8 = 0.0f;
        #pragma unroll
        for (int p = 0; p < 8; ++p) s8 += xv[p];
        X += s8;
        #pragma unroll
        for (int l = 0; l < 11; ++l) {
            float r = 0.0f;
            #pragma unroll
            for (int p = 0; p < 8; ++p) r = fmaf(xv[p], xv[p+l], r);
            R[l] += r;
        }
        __syncthreads();
    }

    #pragma unroll
    for (int off = 32; off; off >>= 1) {
        X += __shfl_down(X, off);
        #pragma unroll
        for (int l = 0; l < 11; ++l) R[l] += __shfl_down(R[l], off);
    }
    __shared__ float red[4][12];
    int wave = tid >> 6;
    if ((tid & 63) == 0) {
        red[wave][0] = X;
        #pragma unroll
        for (int l = 0; l < 11; ++l) red[wave][1+l] = R[l];
    }
    __syncthreads();
    if (tid < 12)
        part[tid * 1024 + (blockIdx.x - 1)] = red[0][tid] + red[1][tid] + red[2][tid] + red[3][tid];
}

// ============ K2: fold — reduce partials + BN fold into taps/bias (validated R8) ============
__global__ void fold_kernel(const float* __restrict__ part,
                            const float* __restrict__ Kraw,
                            const float* __restrict__ gamma, const float* __restrict__ beta,
                            float* __restrict__ Kscl, float* __restrict__ biasv) {
    __shared__ double vals[12];
    __shared__ float Kr[220];
    __shared__ float g[4];
    int tid = threadIdx.x;
    int w = tid >> 6, lane = tid & 63;
    if (tid < 220) Kr[tid] = Kraw[tid];
    for (int v = w; v < 12; v += 4) {
        double d = 0.0;
        #pragma unroll 4
        for (int i = 0; i < 16; ++i) d += (double)part[v * 1024 + i * 64 + lane];
        #pragma unroll
        for (int off = 32; off; off >>= 1) d += __shfl_down(d, off);
        if (lane == 0) vals[v] = d;
    }
    __syncthreads();
    if (tid < 4) {
        int c = tid;
        const float* Kc = Kr + 176 + c * 11;
        double sK = 0.0;
        for (int j = 0; j < 11; ++j) sK += (double)Kc[j];
        double mean = sK * vals[0] / NTOT;
        double ex2 = 0.0;
        for (int l = 0; l < 11; ++l) {
            double A = 0.0;
            for (int j = 0; j + l < 11; ++j) A += (double)Kc[j] * (double)Kc[j+l];
            ex2 += (l ? 2.0 : 1.0) * A * vals[1+l];
        }
        ex2 /= NTOT;
        double var = ex2 - mean * mean;
        float gg = gamma[c] * (float)(1.0 / sqrt(var + 1e-5));
        g[c] = gg;
        biasv[c] = beta[c] - (float)mean * gg;
    }
    __syncthreads();
    if (tid < 220) {
        int c = (tid / 11) % 4;
        Kscl[tid] = Kr[tid] * g[c];
    }
}

// ============ K3: write pass — EXACT R7 structure; fast-path stores nontemporal ============
// grid 4096 = 32 rows x 128 segs; 1 tile/block; thread = 4 outs x 2 half-tiles x 4 ch.
// Lane-contiguous 16B-aligned dwordx4 stores (wave = 1KB full lines -> nt safe).
__global__ __launch_bounds__(256, 4) void write_kernel(const float* __restrict__ x,
                                                       const float* __restrict__ Kscl,
                                                       const float* __restrict__ biasv,
                                                       float* __restrict__ out) {
    __shared__ float xt[2064];
    int tid = threadIdx.x;
    int b = blockIdx.x >> 7, seg = blockIdx.x & 127;
    int base = seg << 11;
    const float* xb = x + b * L_LEN;

    *(float4*)&xt[4*tid]        = *(const float4*)(xb + base + 4*tid);
    *(float4*)&xt[1024 + 4*tid] = *(const float4*)(xb + base + 1024 + 4*tid);
    if (tid < 4) {
        float4 v = {0.f,0.f,0.f,0.f};
        if (seg < 127) v = *(const float4*)(xb + base + 2048 + 4*tid);
        *(float4*)&xt[2048 + 4*tid] = v;
    }

    float K[4][11], bias[4];
    #pragma unroll
    for (int c = 0; c < 4; ++c) {
        #pragma unroll
        for (int j = 0; j < 11; ++j) K[c][j] = Kscl[176 + c*11 + j];
        bias[c] = biasv[c];
    }
    __syncthreads();

    #pragma unroll
    for (int gdx = 0; gdx < 2; ++gdx) {
        int lt = gdx * 1024 + 4 * tid;
        bool scalar = (seg == 127) && (gdx == 1) && (tid >= 253);
        if (!scalar) {
            float xv[16];
            const float4* xr = (const float4*)&xt[lt];
            #pragma unroll
            for (int i = 0; i < 4; ++i) {
                float4 a = xr[i];
                xv[4*i]=a.x; xv[4*i+1]=a.y; xv[4*i+2]=a.z; xv[4*i+3]=a.w;
            }
            #pragma unroll
            for (int c = 0; c < 4; ++c) {
                int sh = (c & 1) ? 2 : 0;
                float v[4];
                #pragma unroll
                for (int p = 0; p < 4; ++p) {
                    float a = bias[c];
                    #pragma unroll
                    for (int j = 0; j < 11; ++j) a = fmaf(K[c][j], xv[sh+p+j], a);
                    v[p] = fmaxf(a, 0.0f);
                }
                float* op = out + (size_t)(4*b + c) * OUT_LEN + base + sh + lt;
                __builtin_nontemporal_store((v4f){v[0], v[1], v[2], v[3]}, (v4f*)op);
            }
        } else {
            #pragma unroll
            for (int par = 0; par < 2; ++par) {
                int sh = 2 * par;
                for (int p = 0; p < 4; ++p) {
                    int t = base + sh + lt + p;
                    if (t >= OUT_LEN) continue;
                    int rem = L_LEN - t;
                    int q = (rem - 3) >> 1; if (q > 4) q = 4;
                    int kmax = 2 * q + 3;
                    int li = sh + lt + p;
                    for (int c = par; c < 4; c += 2) {
                        float a = bias[c];
                        for (int j = 0; j < kmax; ++j) a = fmaf(Kscl[q*44 + c*11 + j], xt[li + j], a);
                        out[(size_t)(4*b + c) * OUT_LEN + t] = fmaxf(a, 0.0f);
                    }
                }
            }
        }
    }
    if (seg == 0 && tid == 0) {
        for (int c = 1; c < 4; c += 2) {
            for (int t = 0; t < 2; ++t) {
                float a = bias[c];
                #pragma unroll
                for (int j = 0; j < 11; ++j) a = fmaf(K[c][j], xt[t + j], a);
                out[(size_t)(4*b + c) * OUT_LEN + t] = fmaxf(a, 0.0f);
            }
        }
    }
}

extern "C" void kernel_launch(void* const* d_in, const int* in_sizes, int n_in,
                              void* d_out, int out_size, void* d_ws, size_t ws_size,
                              hipStream_t stream) {
    const float* x     = (const float*)d_in[0];
    const float* w1    = (const float*)d_in[1];
    const float* b1    = (const float*)d_in[2];
    const float* w2    = (const float*)d_in[3];
    const float* b2    = (const float*)d_in[4];
    const float* gamma = (const float*)d_in[5];
    const float* beta  = (const float*)d_in[6];
    KPtrs kp;
    for (int i = 0; i < 12; ++i) kp.p[i] = (const float*)d_in[7 + i];
    float* out = (float*)d_out;

    char* ws = (char*)d_ws;
    float* Kraw  = (float*)(ws + 1024);     // 220 floats
    float* Kscl  = (float*)(ws + 2048);     // 220 floats
    float* biasv = (float*)(ws + 3072);     // 4 floats
    float* part  = (float*)(ws + 4096);     // 12*1024 floats = 48 KB

    stats_mlp_kernel<<<dim3(1025), dim3(256), 0, stream>>>(x, w1, b1, w2, b2, kp, part, Kraw);
    fold_kernel<<<dim3(1), dim3(256), 0, stream>>>(part, Kraw, gamma, beta, Kscl, biasv);
    write_kernel<<<dim3(4096), dim3(256), 0, stream>>>(x, Kscl, biasv, out);
}

// Round 14
// 101.907 us; speedup vs baseline: 1.6287x; 1.0424x over previous
//
#include <hip/hip_runtime.h>

#define L_LEN   262144
#define OUT_LEN 262142
#define NTOT    (32.0 * 262142.0)

typedef float v4f __attribute__((ext_vector_type(4)));

struct KPtrs { const float* p[12]; };

// ============ K1: block 0 = self-pool + MLP -> Kraw ; blocks 1..1024 = autocorr stats ============
// (validated R11/R12/R13). part SoA: part[v*1024 + (blk-1)], v=0 -> X, v=1+l -> R_l.
__global__ __launch_bounds__(256, 4) void stats_mlp_kernel(const float* __restrict__ x,
                                                           const float* __restrict__ w1,
                                                           const float* __restrict__ b1,
                                                           const float* __restrict__ w2,
                                                           const float* __restrict__ b2,
                                                           KPtrs kp,
                                                           float* __restrict__ part,
                                                           float* __restrict__ Kraw) {
    int tid = threadIdx.x;

    if (blockIdx.x == 0) {
        __shared__ float pooledL[256];
        __shared__ float h[128];
        __shared__ float lgt[12];
        __shared__ float sm[12];
        {
            float s = 0.0f;
            const float4* xq = (const float4*)(x + (size_t)1024 * tid);
            #pragma unroll 8
            for (int i = 0; i < 256; ++i) {
                float4 v = xq[i];
                s += (v.x + v.y) + (v.z + v.w);
            }
            pooledL[tid] = s * (1.0f / 1024.0f);
        }
        __syncthreads();
        int w = tid >> 6, lane = tid & 63;
        float4 pv = *(const float4*)&pooledL[4 * lane];
        for (int i = 0; i < 32; ++i) {
            int t = w * 32 + i;
            float4 wv = ((const float4*)(w1 + t * 256))[lane];
            float p = wv.x*pv.x + wv.y*pv.y + wv.z*pv.z + wv.w*pv.w;
            #pragma unroll
            for (int off = 32; off; off >>= 1) p += __shfl_down(p, off);
            if (lane == 0) h[t] = fmaxf(p + b1[t], 0.0f);
        }
        __syncthreads();
        for (int f = w; f < 12; f += 4) {
            float2 wv = ((const float2*)(w2 + f * 128))[lane];
            float p = wv.x * h[2*lane] + wv.y * h[2*lane + 1];
            #pragma unroll
            for (int off = 32; off; off >>= 1) p += __shfl_down(p, off);
            if (lane == 0) lgt[f] = p + b2[f];
        }
        __syncthreads();
        if (tid == 0) {
            float m = lgt[0];
            #pragma unroll
            for (int i = 1; i < 12; ++i) m = fmaxf(m, lgt[i]);
            float e[12]; float sum = 0.0f;
            #pragma unroll
            for (int i = 0; i < 12; ++i) { e[i] = expf(lgt[i] - m); sum += e[i]; }
            float inv = 1.0f / sum;
            #pragma unroll
            for (int i = 0; i < 12; ++i) sm[i] = e[i] * inv;
        }
        __syncthreads();
        constexpr int KSa[12] = {3,3,3,5,5,7,7,7,9,9,11,11};
        if (tid < 220) {
            int q = tid / 44, r = tid % 44, c = r / 11, j = r % 11;
            int kmax = 2 * q + 3;
            float v = 0.0f;
            #pragma unroll
            for (int i = 0; i < 12; ++i) {
                int k = KSa[i];
                if (k <= kmax && j < k) v = fmaf(sm[i], kp.p[i][c * k + j], v);
            }
            Kraw[tid] = v;
        }
        return;
    }

    __shared__ float xt[2064];
    float X = 0.0f, R[11];
    #pragma unroll
    for (int l = 0; l < 11; ++l) R[l] = 0.0f;

    for (int it = 0; it < 4; ++it) {
        int T = (blockIdx.x - 1) * 4 + it;
        int row = T >> 7, seg = T & 127;
        int base = seg << 11;
        const float* xb = x + row * L_LEN;
        *(float4*)&xt[4*tid]        = *(const float4*)(xb + base + 4*tid);
        *(float4*)&xt[1024 + 4*tid] = *(const float4*)(xb + base + 1024 + 4*tid);
        if (tid < 3) {
            float4 v = {0.f,0.f,0.f,0.f};
            if (seg < 127) v = *(const float4*)(xb + base + 2048 + 4*tid);
            *(float4*)&xt[2048 + 4*tid] = v;
        }
        __syncthreads();

        float xv[18];
        const float4* xr = (const float4*)&xt[8*tid];
        #pragma unroll
        for (int i = 0; i < 4; ++i) {
            float4 a = xr[i];
            xv[4*i]=a.x; xv[4*i+1]=a.y; xv[4*i+2]=a.z; xv[4*i+3]=a.w;
        }
        float2 a4 = *(const float2*)&xt[8*tid + 16];
        xv[16]=a4.x; xv[17]=a4.y;

        float s8 = 0.0f;
        #pragma unroll
        for (int p = 0; p < 8; ++p) s8 += xv[p];
        X += s8;
        #pragma unroll
        for (int l = 0; l < 11; ++l) {
            float r = 0.0f;
            #pragma unroll
            for (int p = 0; p < 8; ++p) r = fmaf(xv[p], xv[p+l], r);
            R[l] += r;
        }
        __syncthreads();
    }

    #pragma unroll
    for (int off = 32; off; off >>= 1) {
        X += __shfl_down(X, off);
        #pragma unroll
        for (int l = 0; l < 11; ++l) R[l] += __shfl_down(R[l], off);
    }
    __shared__ float red[4][12];
    int wave = tid >> 6;
    if ((tid & 63) == 0) {
        red[wave][0] = X;
        #pragma unroll
        for (int l = 0; l < 11; ++l) red[wave][1+l] = R[l];
    }
    __syncthreads();
    if (tid < 12)
        part[tid * 1024 + (blockIdx.x - 1)] = red[0][tid] + red[1][tid] + red[2][tid] + red[3][tid];
}

// ============ K2: fold — reduce partials + BN fold into taps/bias (validated R8/R13) ============
__global__ void fold_kernel(const float* __restrict__ part,
                            const float* __restrict__ Kraw,
                            const float* __restrict__ gamma, const float* __restrict__ beta,
                            float* __restrict__ Kscl, float* __restrict__ biasv) {
    __shared__ double vals[12];
    __shared__ float Kr[220];
    __shared__ float g[4];
    int tid = threadIdx.x;
    int w = tid >> 6, lane = tid & 63;
    if (tid < 220) Kr[tid] = Kraw[tid];
    for (int v = w; v < 12; v += 4) {
        double d = 0.0;
        #pragma unroll 4
        for (int i = 0; i < 16; ++i) d += (double)part[v * 1024 + i * 64 + lane];
        #pragma unroll
        for (int off = 32; off; off >>= 1) d += __shfl_down(d, off);
        if (lane == 0) vals[v] = d;
    }
    __syncthreads();
    if (tid < 4) {
        int c = tid;
        const float* Kc = Kr + 176 + c * 11;
        double sK = 0.0;
        for (int j = 0; j < 11; ++j) sK += (double)Kc[j];
        double mean = sK * vals[0] / NTOT;
        double ex2 = 0.0;
        for (int l = 0; l < 11; ++l) {
            double A = 0.0;
            for (int j = 0; j + l < 11; ++j) A += (double)Kc[j] * (double)Kc[j+l];
            ex2 += (l ? 2.0 : 1.0) * A * vals[1+l];
        }
        ex2 /= NTOT;
        double var = ex2 - mean * mean;
        float gg = gamma[c] * (float)(1.0 / sqrt(var + 1e-5));
        g[c] = gg;
        biasv[c] = beta[c] - (float)mean * gg;
    }
    __syncthreads();
    if (tid < 220) {
        int c = (tid / 11) % 4;
        Kscl[tid] = Kr[tid] * g[c];
    }
}

// ============ K3: write pass — EXACT R7 structure, plain cached dwordx4 stores ============
// grid 4096 = 32 rows x 128 segs; 1 tile/block; thread = 4 outs x 2 half-tiles x 4 ch.
__global__ __launch_bounds__(256, 4) void write_kernel(const float* __restrict__ x,
                                                       const float* __restrict__ Kscl,
                                                       const float* __restrict__ biasv,
                                                       float* __restrict__ out) {
    __shared__ float xt[2064];
    int tid = threadIdx.x;
    int b = blockIdx.x >> 7, seg = blockIdx.x & 127;
    int base = seg << 11;
    const float* xb = x + b * L_LEN;

    *(float4*)&xt[4*tid]        = *(const float4*)(xb + base + 4*tid);
    *(float4*)&xt[1024 + 4*tid] = *(const float4*)(xb + base + 1024 + 4*tid);
    if (tid < 4) {
        float4 v = {0.f,0.f,0.f,0.f};
        if (seg < 127) v = *(const float4*)(xb + base + 2048 + 4*tid);
        *(float4*)&xt[2048 + 4*tid] = v;
    }

    float K[4][11], bias[4];
    #pragma unroll
    for (int c = 0; c < 4; ++c) {
        #pragma unroll
        for (int j = 0; j < 11; ++j) K[c][j] = Kscl[176 + c*11 + j];
        bias[c] = biasv[c];
    }
    __syncthreads();

    #pragma unroll
    for (int gdx = 0; gdx < 2; ++gdx) {
        int lt = gdx * 1024 + 4 * tid;
        bool scalar = (seg == 127) && (gdx == 1) && (tid >= 253);
        if (!scalar) {
            float xv[16];
            const float4* xr = (const float4*)&xt[lt];
            #pragma unroll
            for (int i = 0; i < 4; ++i) {
                float4 a = xr[i];
                xv[4*i]=a.x; xv[4*i+1]=a.y; xv[4*i+2]=a.z; xv[4*i+3]=a.w;
            }
            #pragma unroll
            for (int c = 0; c < 4; ++c) {
                int sh = (c & 1) ? 2 : 0;
                float v[4];
                #pragma unroll
                for (int p = 0; p < 4; ++p) {
                    float a = bias[c];
                    #pragma unroll
                    for (int j = 0; j < 11; ++j) a = fmaf(K[c][j], xv[sh+p+j], a);
                    v[p] = fmaxf(a, 0.0f);
                }
                float* op = out + (size_t)(4*b + c) * OUT_LEN + base + sh + lt;
                *(v4f*)op = (v4f){v[0], v[1], v[2], v[3]};
            }
        } else {
            #pragma unroll
            for (int par = 0; par < 2; ++par) {
                int sh = 2 * par;
                for (int p = 0; p < 4; ++p) {
                    int t = base + sh + lt + p;
                    if (t >= OUT_LEN) continue;
                    int rem = L_LEN - t;
                    int q = (rem - 3) >> 1; if (q > 4) q = 4;
                    int kmax = 2 * q + 3;
                    int li = sh + lt + p;
                    for (int c = par; c < 4; c += 2) {
                        float a = bias[c];
                        for (int j = 0; j < kmax; ++j) a = fmaf(Kscl[q*44 + c*11 + j], xt[li + j], a);
                        out[(size_t)(4*b + c) * OUT_LEN + t] = fmaxf(a, 0.0f);
                    }
                }
            }
        }
    }
    if (seg == 0 && tid == 0) {
        for (int c = 1; c < 4; c += 2) {
            for (int t = 0; t < 2; ++t) {
                float a = bias[c];
                #pragma unroll
                for (int j = 0; j < 11; ++j) a = fmaf(K[c][j], xt[t + j], a);
                out[(size_t)(4*b + c) * OUT_LEN + t] = fmaxf(a, 0.0f);
            }
        }
    }
}

extern "C" void kernel_launch(void* const* d_in, const int* in_sizes, int n_in,
                              void* d_out, int out_size, void* d_ws, size_t ws_size,
                              hipStream_t stream) {
    const float* x     = (const float*)d_in[0];
    const float* w1    = (const float*)d_in[1];
    const float* b1    = (const float*)d_in[2];
    const float* w2    = (const float*)d_in[3];
    const float* b2    = (const float*)d_in[4];
    const float* gamma = (const float*)d_in[5];
    const float* beta  = (const float*)d_in[6];
    KPtrs kp;
    for (int i = 0; i < 12; ++i) kp.p[i] = (const float*)d_in[7 + i];
    float* out = (float*)d_out;

    char* ws = (char*)d_ws;
    float* Kraw  = (float*)(ws + 1024);     // 220 floats
    float* Kscl  = (float*)(ws + 2048);     // 220 floats
    float* biasv = (float*)(ws + 3072);     // 4 floats
    float* part  = (float*)(ws + 4096);     // 12*1024 floats = 48 KB

    stats_mlp_kernel<<<dim3(1025), dim3(256), 0, stream>>>(x, w1, b1, w2, b2, kp, part, Kraw);
    fold_kernel<<<dim3(1), dim3(256), 0, stream>>>(part, Kraw, gamma, beta, Kscl, biasv);
    write_kernel<<<dim3(4096), dim3(256), 0, stream>>>(x, Kscl, biasv, out);
}

// Round 15
// 65.400 us; speedup vs baseline: 2.5378x; 1.5582x over previous
//
#include <hip/hip_runtime.h>

#define L_LEN   262144
#define OUT_LEN 262142
#define BATCH   32
#define NTOT    (32.0 * 262142.0)

typedef float v4f __attribute__((ext_vector_type(4)));

struct KPtrs { const float* p[12]; };

// ============ K1: fused pool + autocorrelation stats (R7-validated, 65.2us total) ============
// grid 1024 x 256. Block handles 4 consecutive 2048-tiles (128 tiles/row, 4096 total).
// X = sum(x), R_l = sum(x_u*x_{u+l}) l=0..10 per block (row-local; staging zero-pads
// past row end). Blocks 0..31 also emit pooled bins (row 0) from the LDS-staged tile.
// part SoA: part[v*1024 + block], v=0 -> X, v=1+l -> R_l.
__global__ __launch_bounds__(256, 4) void stats_pool_kernel(const float* __restrict__ x,
                                                            float* __restrict__ part,
                                                            float* __restrict__ pooled) {
    __shared__ float xt[2064];
    __shared__ float wsum[4];
    int tid = threadIdx.x;
    float X = 0.0f, R[11];
    #pragma unroll
    for (int l = 0; l < 11; ++l) R[l] = 0.0f;

    for (int it = 0; it < 4; ++it) {
        int T = blockIdx.x * 4 + it;       // 0..4095
        int row = T >> 7, seg = T & 127;   // row 0..31, seg 0..127
        int base = seg << 11;
        const float* xb = x + row * L_LEN;
        *(float4*)&xt[4 * tid]        = *(const float4*)(xb + base + 4 * tid);
        *(float4*)&xt[1024 + 4 * tid] = *(const float4*)(xb + base + 1024 + 4 * tid);
        if (tid < 3) {
            float4 v = {0.f, 0.f, 0.f, 0.f};
            if (seg < 127) v = *(const float4*)(xb + base + 2048 + 4 * tid);
            *(float4*)&xt[2048 + 4 * tid] = v;
        }
        __syncthreads();

        float xv[18];
        const float4* xr = (const float4*)&xt[8 * tid];
        #pragma unroll
        for (int i = 0; i < 4; ++i) {
            float4 a = xr[i];
            xv[4*i] = a.x; xv[4*i+1] = a.y; xv[4*i+2] = a.z; xv[4*i+3] = a.w;
        }
        float2 a4 = *(const float2*)&xt[8 * tid + 16];
        xv[16] = a4.x; xv[17] = a4.y;

        float s8 = 0.0f;
        #pragma unroll
        for (int p = 0; p < 8; ++p) s8 += xv[p];
        X += s8;
        #pragma unroll
        for (int l = 0; l < 11; ++l) {
            float r = 0.0f;
            #pragma unroll
            for (int p = 0; p < 8; ++p) r = fmaf(xv[p], xv[p + l], r);
            R[l] += r;
        }

        if (blockIdx.x < 32) {
            // row 0: this tile covers pooled bins 8*block + 2*it + {0,1}
            float ps = s8;
            #pragma unroll
            for (int off = 32; off; off >>= 1) ps += __shfl_down(ps, off);
            if ((tid & 63) == 0) wsum[tid >> 6] = ps;
            __syncthreads();
            if (tid == 0) {
                pooled[blockIdx.x * 8 + 2 * it]     = (wsum[0] + wsum[1]) * (1.0f / 1024.0f);
                pooled[blockIdx.x * 8 + 2 * it + 1] = (wsum[2] + wsum[3]) * (1.0f / 1024.0f);
            }
        }
        __syncthreads();
    }

    // block-reduce 12 values -> part
    #pragma unroll
    for (int off = 32; off; off >>= 1) {
        X += __shfl_down(X, off);
        #pragma unroll
        for (int l = 0; l < 11; ++l) R[l] += __shfl_down(R[l], off);
    }
    __shared__ float red[4][12];
    int wave = tid >> 6;
    if ((tid & 63) == 0) {
        red[wave][0] = X;
        #pragma unroll
        for (int l = 0; l < 11; ++l) red[wave][1 + l] = R[l];
    }
    __syncthreads();
    if (tid < 12)
        part[tid * 1024 + blockIdx.x] = red[0][tid] + red[1][tid] + red[2][tid] + red[3][tid];
}

// ============ K2: attention MLP + softmax + partial reduce + BN fold ============
// 1 block x 1024 threads (16 waves -> layer-1 serial depth 8).
__global__ void attn_finalize_kernel(const float* __restrict__ w1, const float* __restrict__ b1,
                                     const float* __restrict__ w2, const float* __restrict__ b2,
                                     KPtrs kp, const float* __restrict__ pooled,
                                     const float* __restrict__ part,
                                     const float* __restrict__ gamma, const float* __restrict__ beta,
                                     float* __restrict__ Kscl, float* __restrict__ biasv) {
    __shared__ float h[128];
    __shared__ float logits[12];
    __shared__ float s[12];
    __shared__ float Kr[220];
    __shared__ double vals[12];
    __shared__ float g[4];
    int tid = threadIdx.x;
    int w = tid >> 6, lane = tid & 63;

    float4 pv = ((const float4*)pooled)[lane];
    // layer 1: wave w rows 8w .. 8w+7
    for (int i = 0; i < 8; ++i) {
        int t = w * 8 + i;
        float4 wv = ((const float4*)(w1 + t * 256))[lane];
        float p = wv.x * pv.x + wv.y * pv.y + wv.z * pv.z + wv.w * pv.w;
        #pragma unroll
        for (int off = 32; off; off >>= 1) p += __shfl_down(p, off);
        if (lane == 0) h[t] = fmaxf(p + b1[t], 0.0f);
    }
    __syncthreads();
    // layer 2: waves 0..11, one row each
    if (w < 12) {
        float2 wv = ((const float2*)(w2 + w * 128))[lane];
        float p = wv.x * h[2 * lane] + wv.y * h[2 * lane + 1];
        #pragma unroll
        for (int off = 32; off; off >>= 1) p += __shfl_down(p, off);
        if (lane == 0) logits[w] = p + b2[w];
    }
    __syncthreads();
    if (tid == 0) {
        float m = logits[0];
        #pragma unroll
        for (int i = 1; i < 12; ++i) m = fmaxf(m, logits[i]);
        float e[12]; float sum = 0.0f;
        #pragma unroll
        for (int i = 0; i < 12; ++i) { e[i] = expf(logits[i] - m); sum += e[i]; }
        float inv = 1.0f / sum;
        #pragma unroll
        for (int i = 0; i < 12; ++i) s[i] = e[i] * inv;
    }
    __syncthreads();
    constexpr int KSa[12] = {3,3,3,5,5,7,7,7,9,9,11,11};
    if (tid < 220) {
        int q = tid / 44, r = tid % 44, c = r / 11, j = r % 11;
        int kmax = 2 * q + 3;
        float v = 0.0f;
        #pragma unroll
        for (int i = 0; i < 12; ++i) {
            int k = KSa[i];
            if (k <= kmax && j < k) v = fmaf(s[i], kp.p[i][c * k + j], v);
        }
        Kr[tid] = v;
    }
    // reduce partials: wave w (w<12) handles value w over 1024 blocks
    if (w < 12) {
        double d = 0.0;
        #pragma unroll 4
        for (int i = 0; i < 16; ++i) d += (double)part[w * 1024 + i * 64 + lane];
        #pragma unroll
        for (int off = 32; off; off >>= 1) d += __shfl_down(d, off);
        if (lane == 0) vals[w] = d;
    }
    __syncthreads();
    if (tid < 4) {
        int c = tid;
        const float* Kc = Kr + 4 * 44 + c * 11;   // full-kernel class
        double sK = 0.0;
        for (int j = 0; j < 11; ++j) sK += (double)Kc[j];
        double mean = sK * vals[0] / NTOT;
        double ex2 = 0.0;
        for (int l = 0; l < 11; ++l) {
            double A = 0.0;
            for (int j = 0; j + l < 11; ++j) A += (double)Kc[j] * (double)Kc[j + l];
            ex2 += (l ? 2.0 : 1.0) * A * vals[1 + l];
        }
        ex2 /= NTOT;
        double var = ex2 - mean * mean;
        float gg = gamma[c] * (float)(1.0 / sqrt(var + 1e-5));
        g[c] = gg;
        biasv[c] = beta[c] - (float)mean * gg;
    }
    __syncthreads();
    if (tid < 220) {
        int c = (tid / 11) % 4;
        Kscl[tid] = Kr[tid] * g[c];
    }
}

// ============ K3: write pass — 2048-tile, lane-contiguous dwordx4 stores ============
// grid 4096 = 32 rows x 128 segs. Thread = 4 consecutive outputs x 2 half-tiles x 4 ch.
// Odd channels shifted +2 (row base ≡ 2 mod 4) so every store is 16B-aligned dwordx4
// with 16B lane stride (wave writes 1KB contiguous). Head/tail scalar fixups.
__global__ __launch_bounds__(256, 4) void write_kernel(const float* __restrict__ x,
                                                       const float* __restrict__ Kscl,
                                                       const float* __restrict__ biasv,
                                                       float* __restrict__ out) {
    __shared__ float xt[2064];
    int tid = threadIdx.x;
    int b = blockIdx.x >> 7, seg = blockIdx.x & 127;
    int base = seg << 11;
    const float* xb = x + b * L_LEN;

    *(float4*)&xt[4 * tid]        = *(const float4*)(xb + base + 4 * tid);
    *(float4*)&xt[1024 + 4 * tid] = *(const float4*)(xb + base + 1024 + 4 * tid);
    if (tid < 4) {
        float4 v = {0.f, 0.f, 0.f, 0.f};
        if (seg < 127) v = *(const float4*)(xb + base + 2048 + 4 * tid);
        *(float4*)&xt[2048 + 4 * tid] = v;
    }

    float K[4][11], bias[4];
    #pragma unroll
    for (int c = 0; c < 4; ++c) {
        #pragma unroll
        for (int j = 0; j < 11; ++j) K[c][j] = Kscl[4 * 44 + c * 11 + j];
        bias[c] = biasv[c];
    }
    __syncthreads();

    #pragma unroll
    for (int gdx = 0; gdx < 2; ++gdx) {
        int lt = gdx * 1024 + 4 * tid;
        bool scalar = (seg == 127) && (gdx == 1) && (tid >= 253);
        if (!scalar) {
            float xv[16];
            const float4* xr = (const float4*)&xt[lt];
            #pragma unroll
            for (int i = 0; i < 4; ++i) {
                float4 a = xr[i];
                xv[4*i] = a.x; xv[4*i+1] = a.y; xv[4*i+2] = a.z; xv[4*i+3] = a.w;
            }
            #pragma unroll
            for (int c = 0; c < 4; ++c) {
                int sh = (c & 1) ? 2 : 0;
                float v[4];
                #pragma unroll
                for (int p = 0; p < 4; ++p) {
                    float a = bias[c];
                    #pragma unroll
                    for (int j = 0; j < 11; ++j) a = fmaf(K[c][j], xv[sh + p + j], a);
                    v[p] = fmaxf(a, 0.0f);
                }
                // addr ≡ 0 mod 4 floats: row base %4 = {0,2}, sh = {0,2} cancels
                float* op = out + (size_t)(4 * b + c) * OUT_LEN + base + sh + lt;
                *(v4f*)op = (v4f){v[0], v[1], v[2], v[3]};
            }
        } else {
            // seg==127, half-tile B, tid>=253: per-position cumulative-class + bounds
            #pragma unroll
            for (int par = 0; par < 2; ++par) {
                int sh = 2 * par;
                for (int p = 0; p < 4; ++p) {
                    int t = base + sh + lt + p;
                    if (t >= OUT_LEN) continue;
                    int rem = L_LEN - t;
                    int q = (rem - 3) >> 1; if (q > 4) q = 4;
                    int kmax = 2 * q + 3;
                    int li = sh + lt + p;
                    for (int c = par; c < 4; c += 2) {
                        float a = bias[c];
                        for (int j = 0; j < kmax; ++j) a = fmaf(Kscl[q * 44 + c * 11 + j], xt[li + j], a);
                        out[(size_t)(4 * b + c) * OUT_LEN + t] = fmaxf(a, 0.0f);
                    }
                }
            }
        }
    }
    // head: odd channels' outputs t=0,1 (not covered by shifted quads)
    if (seg == 0 && tid == 0) {
        for (int c = 1; c < 4; c += 2) {
            for (int t = 0; t < 2; ++t) {
                float a = bias[c];
                #pragma unroll
                for (int j = 0; j < 11; ++j) a = fmaf(K[c][j], xt[t + j], a);
                out[(size_t)(4 * b + c) * OUT_LEN + t] = fmaxf(a, 0.0f);
            }
        }
    }
}

extern "C" void kernel_launch(void* const* d_in, const int* in_sizes, int n_in,
                              void* d_out, int out_size, void* d_ws, size_t ws_size,
                              hipStream_t stream) {
    const float* x     = (const float*)d_in[0];
    const float* w1    = (const float*)d_in[1];
    const float* b1    = (const float*)d_in[2];
    const float* w2    = (const float*)d_in[3];
    const float* b2    = (const float*)d_in[4];
    const float* gamma = (const float*)d_in[5];
    const float* beta  = (const float*)d_in[6];
    KPtrs kp;
    for (int i = 0; i < 12; ++i) kp.p[i] = (const float*)d_in[7 + i];
    float* out = (float*)d_out;

    char* ws = (char*)d_ws;
    float* pooled = (float*)(ws + 0);       // 256 floats
    float* Kscl   = (float*)(ws + 1024);    // 220 floats
    float* biasv  = (float*)(ws + 2048);    // 4 floats
    float* part   = (float*)(ws + 4096);    // 12*1024 floats = 48 KB

    stats_pool_kernel<<<dim3(1024), dim3(256), 0, stream>>>(x, part, pooled);
    attn_finalize_kernel<<<dim3(1), dim3(1024), 0, stream>>>(w1, b1, w2, b2, kp, pooled,
                                                             part, gamma, beta, Kscl, biasv);
    write_kernel<<<dim3(4096), dim3(256), 0, stream>>>(x, Kscl, biasv, out);
}